// Round 9
// baseline (231.159 us; speedup 1.0000x reference)
//
#include <hip/hip_runtime.h>
#include <hip/hip_bf16.h>

typedef unsigned short u16;
typedef __attribute__((ext_vector_type(8))) short short8;
typedef __attribute__((ext_vector_type(4))) float floatx4;
typedef __attribute__((ext_vector_type(16))) float floatx16;
typedef __attribute__((ext_vector_type(4))) unsigned uintx4;

#define LOG2E 1.44269504088896f
#define CEXP (0.125f * LOG2E)   // folded into Q at the QK epilogue

static __device__ __forceinline__ u16 f2b(float f) {
  union { float f; unsigned u; } v; v.f = f;
  unsigned r = v.u + 0x7fffu + ((v.u >> 16) & 1u);
  return (u16)(r >> 16);
}
static __device__ __forceinline__ float b2f(u16 b) {
  union { float f; unsigned u; } v; v.u = ((unsigned)b) << 16;
  return v.f;
}
static __device__ __forceinline__ unsigned pack2bf(float lo, float hi) {
  __hip_bfloat162 a = __float22bfloat162_rn(float2{lo, hi});
  return *(unsigned*)&a;
}
static __device__ __forceinline__ void async16(const u16* g, u16* l) {
  __builtin_amdgcn_global_load_lds(
      (const __attribute__((address_space(1))) unsigned int*)g,
      (__attribute__((address_space(3))) unsigned int*)l, 16, 0, 0);
}
static __device__ __forceinline__ float fexp2(float x) {
  return __builtin_amdgcn_exp2f(x);
}
// row permutation: row-owner block has XCD == (row>>7)%8, so 128-row panels are
// written through the L2 of the XCD that later consumes them.
static __device__ __forceinline__ int rowmap4096(int b) {
  return (b & 7) * 128 + ((b >> 3) & 3) * 1024 + (b >> 5);
}

// ---------------- weights fp32 -> bf16 (x4 vectorized) + per-channel GN stats ----------------
__global__ __launch_bounds__(256) void f2b_all(
    const float* __restrict__ s0, const float* __restrict__ s1, const float* __restrict__ s2,
    const float* __restrict__ s3, const float* __restrict__ s4, const float* __restrict__ s5,
    const float* __restrict__ s6, const float* __restrict__ x,
    u16* __restrict__ d_win, u16* __restrict__ d_qkv, u16* __restrict__ d_f1,
    u16* __restrict__ d_f2, u16* __restrict__ d_wout, float2* __restrict__ cstats) {
  if (blockIdx.x >= 3072) {   // per-channel stats: one block per channel
    int c = blockIdx.x - 3072;
    const float4* p4 = (const float4*)(x + (size_t)c * 4096);
    float s = 0.f, ss = 0.f;
#pragma unroll
    for (int j = 0; j < 4; j++) {
      float4 v = p4[j * 256 + threadIdx.x];
      s += v.x + v.y + v.z + v.w;
      ss += v.x * v.x + v.y * v.y + v.z * v.z + v.w * v.w;
    }
    for (int m = 1; m < 64; m <<= 1) { s += __shfl_xor(s, m); ss += __shfl_xor(ss, m); }
    __shared__ float sb[8];
    int w = threadIdx.x >> 6;
    if ((threadIdx.x & 63) == 0) { sb[w * 2] = s; sb[w * 2 + 1] = ss; }
    __syncthreads();
    if (threadIdx.x == 0)
      cstats[c] = float2{sb[0] + sb[2] + sb[4] + sb[6], sb[1] + sb[3] + sb[5] + sb[7]};
    return;
  }
  int i = blockIdx.x * 256 + threadIdx.x;   // x4 elements per thread
  const float* src;
  u16* dst;
  if (i < 32768) { src = s0; dst = d_win; }
  else if ((i -= 32768) < 65536) { src = s1; dst = d_qkv; }
  else if ((i -= 65536) < 65536) { src = s2; dst = d_qkv + 262144; }
  else if ((i -= 65536) < 65536) { src = s3; dst = d_qkv + 524288; }
  else if ((i -= 65536) < 262144) { src = s4; dst = d_f1; }
  else if ((i -= 262144) < 262144) { src = s5; dst = d_f2; }
  else { i -= 262144; src = s6; dst = d_wout; }   // i in [0, 32768)
  float4 v = *(const float4*)&src[i * 4];
  ushort4 o;
  o.x = f2b(v.x); o.y = f2b(v.y); o.z = f2b(v.z); o.w = f2b(v.w);
  *(ushort4*)&dst[i * 4] = o;
}

// ---------------- GroupNorm apply + LDS transpose to (N,C) bf16, 512 blocks ----------------
__global__ __launch_bounds__(256) void gn_apply(const float* __restrict__ x, const float2* __restrict__ cstats,
                                                const float* __restrict__ gg, const float* __restrict__ gb,
                                                u16* __restrict__ hn) {
  __shared__ float tile[256 * 9];
  __shared__ float gmu[32], grs[32];
  int t = threadIdx.x;
  if (t < 32) {
    float s = 0.f, ss = 0.f;
#pragma unroll
    for (int j = 0; j < 8; j++) { float2 p = cstats[t * 8 + j]; s += p.x; ss += p.y; }
    float mu = s / 32768.f;
    gmu[t] = mu;
    grs[t] = rsqrtf(ss / 32768.f - mu * mu + 1e-5f);
  }
  __syncthreads();
  int bb = blockIdx.x;
  int g = (bb & 7) * 16 + ((bb >> 3) & 3) * 128 + (bb >> 5);   // (g>>4)%8 == bb%8
  int n0 = g * 8;
#pragma unroll
  for (int j = 0; j < 2; j++) {
    int c = j * 128 + (t >> 1);
    int nl = (t & 1) * 4;
    float4 v = *(const float4*)&x[(size_t)c * 4096 + n0 + nl];
    float ga = gg[c] * grs[c >> 3];
    float bb2 = gb[c] - gmu[c >> 3] * ga;
    tile[c * 9 + nl + 0] = v.x * ga + bb2;
    tile[c * 9 + nl + 1] = v.y * ga + bb2;
    tile[c * 9 + nl + 2] = v.z * ga + bb2;
    tile[c * 9 + nl + 3] = v.w * ga + bb2;
  }
  __syncthreads();
#pragma unroll
  for (int j = 0; j < 8; j++)
    hn[(size_t)(n0 + j) * 256 + t] = f2b(tile[t * 9 + j]);
}

#define FLAG_BIAS 1
#define FLAG_GELU 2
#define FLAG_C16 8
#define FLAG_CZ 64      // C16[z*M*N + m*N + n] = bf16(v), bias on z==0 only

// ---------------- GEMM 128x64 tile (proj_in, ff1, ff2) — dbuf counted-vmcnt pipeline --------
// 256 threads / 4 waves; optional split-K via gridDim.z (FLAG_CZ partials), GELU epilogue.
// 48 KiB LDS -> 3 independent blocks/CU: inter-block phase slip covers lockstep stalls.
__global__ __launch_bounds__(256) void gemm_bt(
    const u16* __restrict__ A, const u16* __restrict__ B, const float* __restrict__ bias,
    u16* __restrict__ C16, int M, int N, int K, int flags) {
  __shared__ u16 As[2][128 * 64];
  __shared__ u16 Bs[2][64 * 64];
  const int t = threadIdx.x;
  const int lane = t & 63;
  const int w = t >> 6;
  const int ln = lane & 15;
  const int quad = lane >> 4;
  const int m0 = blockIdx.x * 128;
  const int n0 = blockIdx.y * 64;
  const int wm = (w >> 1) * 64;
  const int wn = (w & 1) * 32;
  const int kper = K / gridDim.z;
  const int kbeg = blockIdx.z * kper;

  floatx4 acc[4][2];
#pragma unroll
  for (int i = 0; i < 4; i++)
#pragma unroll
    for (int j = 0; j < 2; j++) acc[i][j] = floatx4{0.f, 0.f, 0.f, 0.f};

  auto stage = [&](int b, int k0) {
#pragma unroll
    for (int i = 0; i < 4; ++i) {
      int s = i * 256 + t;
      int row = s >> 3;
      int kb = (s & 7) ^ (row & 7);
      async16(A + (size_t)(m0 + row) * K + k0 + kb * 8, &As[b][(i * 256 + (t & ~63)) * 8]);
    }
#pragma unroll
    for (int i = 0; i < 2; ++i) {
      int s = i * 256 + t;
      int row = s >> 3;
      int kb = (s & 7) ^ (row & 7);
      async16(B + (size_t)(n0 + row) * K + k0 + kb * 8, &Bs[b][(i * 256 + (t & ~63)) * 8]);
    }
  };

  const int nIt = kper >> 6;
  stage(0, kbeg);
  int cur = 0;
  for (int it = 0; it < nIt; ++it) {
    __builtin_amdgcn_s_barrier();
    __builtin_amdgcn_sched_barrier(0);
    if (it + 1 < nIt) {
      stage(cur ^ 1, kbeg + (it + 1) * 64);
      __builtin_amdgcn_sched_barrier(0);
      asm volatile("s_waitcnt vmcnt(6)" ::: "memory");   // drain tile it; 6 new stay in flight
    } else {
      asm volatile("s_waitcnt vmcnt(0)" ::: "memory");
    }
    __builtin_amdgcn_s_barrier();
    __builtin_amdgcn_sched_barrier(0);
    const u16* Ac = As[cur];
    const u16* Bc = Bs[cur];
#pragma unroll
    for (int ksi = 0; ksi < 2; ksi++) {
      short8 af[4], bfr[2];
      int kb = ksi * 4 + quad;
#pragma unroll
      for (int i = 0; i < 4; i++) {
        int m = wm + i * 16 + ln;
        af[i] = *(const short8*)&Ac[(m * 8 + (kb ^ (m & 7))) * 8];
      }
#pragma unroll
      for (int j = 0; j < 2; j++) {
        int n = wn + j * 16 + ln;
        bfr[j] = *(const short8*)&Bc[(n * 8 + (kb ^ (n & 7))) * 8];
      }
#pragma unroll
      for (int i = 0; i < 4; i++)
#pragma unroll
        for (int j = 0; j < 2; j++)
          acc[i][j] = __builtin_amdgcn_mfma_f32_16x16x32_bf16(af[i], bfr[j], acc[i][j], 0, 0, 0);
    }
    cur ^= 1;
  }

  u16* Cdst = (flags & FLAG_CZ) ? C16 + (size_t)blockIdx.z * M * N : C16;
#pragma unroll
  for (int i = 0; i < 4; i++) {
#pragma unroll
    for (int j = 0; j < 2; j++) {
      int n = n0 + wn + j * 16 + ln;
      float bv = ((flags & FLAG_BIAS) && blockIdx.z == 0) ? bias[n] : 0.f;
#pragma unroll
      for (int r = 0; r < 4; r++) {
        int m = m0 + wm + i * 16 + quad * 4 + r;
        float v = acc[i][j][r] + bv;
        if (flags & FLAG_GELU) v = 0.5f * v * (1.f + erff(v * 0.70710678118f));
        if (flags & FLAG_C16) Cdst[(size_t)m * N + n] = f2b(v);
      }
    }
  }
}

// ---------------- GEMM 64x64 tile (proj_out: row-bias + resid fp32), pipelined ----------------
__global__ __launch_bounds__(256) void gemm_s64(
    const u16* __restrict__ A, const u16* __restrict__ B, const float* __restrict__ brow,
    const float* __restrict__ resid, float* __restrict__ C32, int N, int K) {
  __shared__ u16 As[2][64 * 64];
  __shared__ u16 Bs[2][64 * 64];
  const int t = threadIdx.x;
  const int lane = t & 63;
  const int w = t >> 6;
  const int ln = lane & 15;
  const int quad = lane >> 4;
  const int f = blockIdx.x + 4 * blockIdx.y;   // hw flat id; XCD = f%8
  const int x = f & 7;
  const int idx = f >> 3;                      // [0,32)
  const int j5 = idx & 7;
  const int nbx = idx >> 3;                    // [0,4)
  const int nby = 2 * x + (j5 & 1) + 16 * (j5 >> 1);  // (nby>>1)%8 == x
  const int m0 = nbx * 64;
  const int n0 = nby * 64;
  const int wm = (w >> 1) * 32;
  const int wn = (w & 1) * 32;

  floatx4 acc[2][2];
#pragma unroll
  for (int i = 0; i < 2; i++)
#pragma unroll
    for (int j = 0; j < 2; j++) acc[i][j] = floatx4{0.f, 0.f, 0.f, 0.f};

  auto stage = [&](int b, int k0) {
#pragma unroll
    for (int i = 0; i < 2; ++i) {
      int s = i * 256 + t;
      int row = s >> 3;
      int kb = (s & 7) ^ (row & 7);
      async16(A + (size_t)(m0 + row) * K + k0 + kb * 8, &As[b][(i * 256 + (t & ~63)) * 8]);
    }
#pragma unroll
    for (int i = 0; i < 2; ++i) {
      int s = i * 256 + t;
      int row = s >> 3;
      int kb = (s & 7) ^ (row & 7);
      async16(B + (size_t)(n0 + row) * K + k0 + kb * 8, &Bs[b][(i * 256 + (t & ~63)) * 8]);
    }
  };

  const int nIt = K >> 6;
  stage(0, 0);
  int cur = 0;
  for (int it = 0; it < nIt; ++it) {
    __builtin_amdgcn_s_barrier();
    __builtin_amdgcn_sched_barrier(0);
    if (it + 1 < nIt) {
      stage(cur ^ 1, (it + 1) * 64);
      __builtin_amdgcn_sched_barrier(0);
      asm volatile("s_waitcnt vmcnt(4)" ::: "memory");
    } else {
      asm volatile("s_waitcnt vmcnt(0)" ::: "memory");
    }
    __builtin_amdgcn_s_barrier();
    __builtin_amdgcn_sched_barrier(0);
    const u16* Ac = As[cur];
    const u16* Bc = Bs[cur];
#pragma unroll
    for (int ksi = 0; ksi < 2; ksi++) {
      short8 af[2], bfr[2];
      int kb = ksi * 4 + quad;
#pragma unroll
      for (int i = 0; i < 2; i++) {
        int m = wm + i * 16 + ln;
        af[i] = *(const short8*)&Ac[(m * 8 + (kb ^ (m & 7))) * 8];
        int n = wn + i * 16 + ln;
        bfr[i] = *(const short8*)&Bc[(n * 8 + (kb ^ (n & 7))) * 8];
      }
#pragma unroll
      for (int i = 0; i < 2; i++)
#pragma unroll
        for (int j = 0; j < 2; j++)
          acc[i][j] = __builtin_amdgcn_mfma_f32_16x16x32_bf16(af[i], bfr[j], acc[i][j], 0, 0, 0);
    }
    cur ^= 1;
  }

#pragma unroll
  for (int i = 0; i < 2; i++) {
#pragma unroll
    for (int j = 0; j < 2; j++) {
      int n = n0 + wn + j * 16 + ln;
#pragma unroll
      for (int r = 0; r < 4; r++) {
        int m = m0 + wm + i * 16 + quad * 4 + r;
        C32[(size_t)m * N + n] = acc[i][j][r] + brow[m] + resid[(size_t)m * N + n];
      }
    }
  }
}

// ---------------- merged q|k + V^T GEMM, 64x128 tiles, one dispatch, pipelined ----------------
__global__ __launch_bounds__(256) void gemm_qkvt(
    const u16* __restrict__ T, const u16* __restrict__ Wqkv,
    u16* __restrict__ Cq, u16* __restrict__ Ck, u16* __restrict__ CvT) {
  __shared__ u16 As[2][64 * 64];
  __shared__ u16 Bs[2][128 * 64];
  const int t = threadIdx.x;
  const int lane = t & 63;
  const int w = t >> 6;
  const int ln = lane & 15;
  const int quad = lane >> 4;
  const int f = blockIdx.x;        // hw flat; XCD = f%8
  const bool isv = f >= 512;
  const u16* A;
  const u16* B;
  int m0, n0;
  if (!isv) {
    int x = f & 7, idx = f >> 3;
    int j5 = idx & 7, nt = idx >> 3;
    int mt = 2 * x + (j5 & 1) + 16 * (j5 >> 1);
    m0 = mt * 64;
    n0 = nt * 128;
    A = T;
    B = Wqkv;
  } else {
    int b2 = f - 512;
    int x = b2 & 7, idx = b2 >> 3;
    int nt2 = x + 8 * (idx & 3);
    int mt2 = idx >> 2;
    m0 = mt2 * 64;
    n0 = nt2 * 128;
    A = Wqkv + 2 * 512 * 512;   // wv
    B = T;
  }
  const int wm = (w >> 1) * 32;
  const int wn = (w & 1) * 64;

  floatx4 acc[2][4];
#pragma unroll
  for (int i = 0; i < 2; i++)
#pragma unroll
    for (int j = 0; j < 4; j++) acc[i][j] = floatx4{0.f, 0.f, 0.f, 0.f};

  auto stage = [&](int b, int k0) {
#pragma unroll
    for (int i = 0; i < 2; ++i) {
      int s = i * 256 + t;
      int row = s >> 3;
      int kb = (s & 7) ^ (row & 7);
      async16(A + (size_t)(m0 + row) * 512 + k0 + kb * 8, &As[b][(i * 256 + (t & ~63)) * 8]);
    }
#pragma unroll
    for (int i = 0; i < 4; ++i) {
      int s = i * 256 + t;
      int row = s >> 3;
      int kb = (s & 7) ^ (row & 7);
      async16(B + (size_t)(n0 + row) * 512 + k0 + kb * 8, &Bs[b][(i * 256 + (t & ~63)) * 8]);
    }
  };

  stage(0, 0);
  int cur = 0;
  for (int it = 0; it < 8; ++it) {
    __builtin_amdgcn_s_barrier();
    __builtin_amdgcn_sched_barrier(0);
    if (it + 1 < 8) {
      stage(cur ^ 1, (it + 1) * 64);
      __builtin_amdgcn_sched_barrier(0);
      asm volatile("s_waitcnt vmcnt(6)" ::: "memory");
    } else {
      asm volatile("s_waitcnt vmcnt(0)" ::: "memory");
    }
    __builtin_amdgcn_s_barrier();
    __builtin_amdgcn_sched_barrier(0);
    const u16* Ac = As[cur];
    const u16* Bc = Bs[cur];
#pragma unroll
    for (int ksi = 0; ksi < 2; ksi++) {
      short8 af[2], bfr[4];
      int kb = ksi * 4 + quad;
#pragma unroll
      for (int i = 0; i < 2; i++) {
        int m = wm + i * 16 + ln;
        af[i] = *(const short8*)&Ac[(m * 8 + (kb ^ (m & 7))) * 8];
      }
#pragma unroll
      for (int j = 0; j < 4; j++) {
        int n = wn + j * 16 + ln;
        bfr[j] = *(const short8*)&Bc[(n * 8 + (kb ^ (n & 7))) * 8];
      }
#pragma unroll
      for (int i = 0; i < 2; i++)
#pragma unroll
        for (int j = 0; j < 4; j++)
          acc[i][j] = __builtin_amdgcn_mfma_f32_16x16x32_bf16(af[i], bfr[j], acc[i][j], 0, 0, 0);
    }
    cur ^= 1;
  }

#pragma unroll
  for (int i = 0; i < 2; i++) {
#pragma unroll
    for (int j = 0; j < 4; j++) {
      int n = n0 + wn + j * 16 + ln;
#pragma unroll
      for (int r = 0; r < 4; r++) {
        int m = m0 + wm + i * 16 + quad * 4 + r;
        float v = acc[i][j][r];
        if (isv) CvT[(size_t)m * 4096 + n] = f2b(v);
        else if (n < 512) Cq[(size_t)m * 512 + n] = f2b(v * CEXP);   // Q pre-scaled
        else Ck[(size_t)m * 512 + (n - 512)] = f2b(v);
      }
    }
  }
}

// ---------------- flash attention: 32x32x16 MFMA, in-register P exchange, no P LDS ----------
// 512 threads, 8 waves x 32 q; K/V double-buffered with counted vmcnt (verified R7 version).
__global__ __launch_bounds__(512, 4) void attn_kernel(
    const u16* __restrict__ Q, const u16* __restrict__ Km, const u16* __restrict__ VT,
    u16* __restrict__ Opart, float* __restrict__ ML, int Nseq, int kvLen) {
  __shared__ u16 Ks[2][64 * 64];
  __shared__ u16 Vs[2][64 * 64];
  const int t = threadIdx.x;
  const int lane = t & 63;
  const int w = t >> 6;            // 0..7
  const int q32 = lane & 31;       // q column within wave tile
  const int H = lane >> 5;         // lane half
  const int h = blockIdx.y;
  const int q0 = blockIdx.x * 256;
  const int split = blockIdx.z;
  const int kvbase = split * kvLen;
  u16* Opw = Opart + (size_t)split * Nseq * 512;

  // Q B-operand fragments qf[kc]: k = kc*16 + H*8 + v (v=0..7 contiguous bf16)
  short8 qf[4];
#pragma unroll
  for (int kc = 0; kc < 4; kc++)
    qf[kc] = *(const short8*)&Q[(size_t)(q0 + w * 32 + q32) * 512 + h * 64 + kc * 16 + H * 8];

  floatx16 accO[2];
#pragma unroll
  for (int dt = 0; dt < 2; dt++)
#pragma unroll
    for (int r = 0; r < 16; r++) accO[dt][r] = 0.f;
  float lsum = 0.f;

  // staging: 512 chunks of 16B per buffer, one per thread
  const int srow = t >> 3;
  const int skb = (t & 7) ^ (srow & 7);
  const u16* gk = Km + (size_t)(kvbase + srow) * 512 + h * 64 + skb * 8;
  const u16* gv = VT + (size_t)(h * 64 + srow) * Nseq + kvbase + skb * 8;
  const int ldst = (t & ~63) * 8;

  const int nIt = kvLen >> 6;
  async16(gk, &Ks[0][ldst]);
  async16(gv, &Vs[0][ldst]);

  int cur = 0;
  for (int it = 0; it < nIt; ++it) {
    __builtin_amdgcn_s_barrier();
    __builtin_amdgcn_sched_barrier(0);
    if (it + 1 < nIt) {
      async16(gk + (size_t)(it + 1) * 64 * 512, &Ks[cur ^ 1][ldst]);
      async16(gv + (it + 1) * 64, &Vs[cur ^ 1][ldst]);
      __builtin_amdgcn_sched_barrier(0);
      asm volatile("s_waitcnt vmcnt(2)" ::: "memory");
    } else {
      __builtin_amdgcn_sched_barrier(0);
      asm volatile("s_waitcnt vmcnt(0)" ::: "memory");
    }
    __builtin_amdgcn_s_barrier();
    __builtin_amdgcn_sched_barrier(0);

    const u16* Kc = Ks[cur];
    const u16* Vc = Vs[cur];

    // S^T[key][q] = sum_k K[key][k] * Q[q][k]  (two 32-key tiles)
    floatx16 accS[2];
#pragma unroll
    for (int kt = 0; kt < 2; kt++)
#pragma unroll
      for (int r = 0; r < 16; r++) accS[kt][r] = 0.f;
    __builtin_amdgcn_s_setprio(1);
#pragma unroll
    for (int kt = 0; kt < 2; kt++) {
      int key = kt * 32 + q32;   // A-row for this lane
#pragma unroll
      for (int kc = 0; kc < 4; kc++) {
        int hb = kc * 2 + H;     // 8-elem hd-block
        short8 kf = *(const short8*)&Kc[(key * 8 + (hb ^ (key & 7))) * 8];
        accS[kt] = __builtin_amdgcn_mfma_f32_32x32x16_bf16(kf, qf[kc], accS[kt], 0, 0, 0);
      }
    }
    __builtin_amdgcn_s_setprio(0);

    // p = exp2(s) in place (static indices); lsum
#pragma unroll
    for (int kt = 0; kt < 2; kt++)
#pragma unroll
      for (int r = 0; r < 16; r++) {
        float pv = fexp2(accS[kt][r]);
        accS[kt][r] = pv;
        lsum += pv;
      }

    // build P B-fragments in-register and do PV immediately per kch
    __builtin_amdgcn_s_setprio(1);
#pragma unroll
    for (int kch = 0; kch < 4; kch++) {
      const int KT = kch >> 1;
      const int S8 = (kch & 1) * 8;
      // lane-half select with STATIC vector extracts (runtime H only in cndmask)
      float e0 = H ? accS[KT][S8 + 4] : accS[KT][S8 + 0];
      float e1 = H ? accS[KT][S8 + 5] : accS[KT][S8 + 1];
      float e2 = H ? accS[KT][S8 + 6] : accS[KT][S8 + 2];
      float e3 = H ? accS[KT][S8 + 7] : accS[KT][S8 + 3];
      unsigned pk0 = pack2bf(e0, e1);
      unsigned pk1 = pack2bf(e2, e3);
      unsigned rx0 = __shfl_xor(pk0, 32);
      unsigned rx1 = __shfl_xor(pk1, 32);
      uintx4 pwv;
      pwv.x = H ? rx0 : pk0;
      pwv.y = H ? rx1 : pk1;
      pwv.z = H ? pk0 : rx0;
      pwv.w = H ? pk1 : rx1;
      short8 pf = __builtin_bit_cast(short8, pwv);
      int kb2 = kch * 2 + H;   // 8-key block
#pragma unroll
      for (int dt = 0; dt < 2; dt++) {
        int d = dt * 32 + q32;     // A-row for this lane
        short8 vf = *(const short8*)&Vc[(d * 8 + (kb2 ^ (d & 7))) * 8];
        accO[dt] = __builtin_amdgcn_mfma_f32_32x32x16_bf16(vf, pf, accO[dt], 0, 0, 0);
      }
    }
    __builtin_amdgcn_s_setprio(0);
    cur ^= 1;
  }

  lsum += __shfl_xor(lsum, 32);
  const int q = q0 + w * 32 + q32;
#pragma unroll
  for (int dt = 0; dt < 2; dt++) {
#pragma unroll
    for (int g = 0; g < 4; g++) {
      // regs 4g..4g+3 -> d = dt*32 + 8g + 4H + (0..3)
      uint2 pk;
      pk.x = pack2bf(accO[dt][4 * g + 0], accO[dt][4 * g + 1]);
      pk.y = pack2bf(accO[dt][4 * g + 2], accO[dt][4 * g + 3]);
      *(uint2*)&Opw[(size_t)q * 512 + h * 64 + dt * 32 + 8 * g + 4 * H] = pk;
    }
  }
  if (H == 0)
    ML[((size_t)split * 8 + h) * Nseq + q] = lsum;
}

// ---------------- combine 4 splits + bf16 residual + LayerNorm (ln1) -> bf16 ----------------
__global__ __launch_bounds__(256) void ln_attn(
    const u16* __restrict__ Opart, const float* __restrict__ ML,
    const u16* __restrict__ t16, const float* __restrict__ g, const float* __restrict__ be,
    u16* __restrict__ o16) {
  int row = rowmap4096(blockIdx.x);
  int t = threadIdx.x;
  size_t base = (size_t)row * 512;
  int c0 = 2 * t;
  int h = c0 >> 6;
  float lt = 0.f;
#pragma unroll
  for (int s = 0; s < 4; s++) lt += ML[((size_t)s * 8 + h) * 4096 + row];
  float a0 = 0.f, a1 = 0.f;
#pragma unroll
  for (int s = 0; s < 4; s++) {
    unsigned oo = *(const unsigned*)&Opart[(size_t)s * 4096 * 512 + base + c0];
    a0 += b2f((u16)(oo & 0xffff));
    a1 += b2f((u16)(oo >> 16));
  }
  unsigned tt = *(const unsigned*)&t16[base + c0];
  float inv = 1.0f / lt;
  float v0 = a0 * inv + b2f((u16)(tt & 0xffff));
  float v1 = a1 * inv + b2f((u16)(tt >> 16));
  float s = v0 + v1, ss = v0 * v0 + v1 * v1;
  for (int m = 1; m < 64; m <<= 1) { s += __shfl_xor(s, m); ss += __shfl_xor(ss, m); }
  __shared__ float sb[8];
  int w = t >> 6;
  if ((t & 63) == 0) { sb[w * 2] = s; sb[w * 2 + 1] = ss; }
  __syncthreads();
  s = sb[0] + sb[2] + sb[4] + sb[6];
  ss = sb[1] + sb[3] + sb[5] + sb[7];
  float mu = s / 512.f;
  float var = ss / 512.f - mu * mu;
  float rs = rsqrtf(var + 1e-5f);
  float2 gv = *(const float2*)&g[c0];
  float2 bv = *(const float2*)&be[c0];
  u16 r0 = f2b((v0 - mu) * rs * gv.x + bv.x);
  u16 r1 = f2b((v1 - mu) * rs * gv.y + bv.y);
  *(unsigned*)&o16[base + c0] = ((unsigned)r1 << 16) | r0;
}

// ---------------- LN2: (4 bf16 split-K partials + bf16 u) -> LayerNorm -> bf16 ----------------
__global__ __launch_bounds__(256) void ln_ff(
    const u16* __restrict__ zp, const u16* __restrict__ u,
    const float* __restrict__ g, const float* __restrict__ be, u16* __restrict__ o16) {
  int row = rowmap4096(blockIdx.x);
  int t = threadIdx.x;
  size_t base = (size_t)row * 512;
  int c0 = 2 * t;
  unsigned uu = *(const unsigned*)&u[base + c0];
  float v0 = b2f((u16)(uu & 0xffff));
  float v1 = b2f((u16)(uu >> 16));
#pragma unroll
  for (int z = 0; z < 4; z++) {
    unsigned zz = *(const unsigned*)&zp[(size_t)z * 4096 * 512 + base + c0];
    v0 += b2f((u16)(zz & 0xffff));
    v1 += b2f((u16)(zz >> 16));
  }
  float s = v0 + v1, ss = v0 * v0 + v1 * v1;
  for (int m = 1; m < 64; m <<= 1) { s += __shfl_xor(s, m); ss += __shfl_xor(ss, m); }
  __shared__ float sb[8];
  int w = t >> 6;
  if ((t & 63) == 0) { sb[w * 2] = s; sb[w * 2 + 1] = ss; }
  __syncthreads();
  s = sb[0] + sb[2] + sb[4] + sb[6];
  ss = sb[1] + sb[3] + sb[5] + sb[7];
  float mu = s / 512.f;
  float var = ss / 512.f - mu * mu;
  float rs = rsqrtf(var + 1e-5f);
  float2 gv = *(const float2*)&g[c0];
  float2 bv = *(const float2*)&be[c0];
  u16 r0 = f2b((v0 - mu) * rs * gv.x + bv.x);
  u16 r1 = f2b((v1 - mu) * rs * gv.y + bv.y);
  *(unsigned*)&o16[base + c0] = ((unsigned)r1 << 16) | r0;
}

extern "C" void kernel_launch(void* const* d_in, const int* in_sizes, int n_in,
                              void* d_out, int out_size, void* d_ws, size_t ws_size,
                              hipStream_t stream) {
  const float* x = (const float*)d_in[0];
  const float* gn_g = (const float*)d_in[1];
  const float* gn_b = (const float*)d_in[2];
  const float* w_in = (const float*)d_in[3];
  const float* b_in = (const float*)d_in[4];
  const float* wq = (const float*)d_in[5];
  const float* wk = (const float*)d_in[6];
  const float* wv = (const float*)d_in[7];
  const float* ln1_g = (const float*)d_in[8];
  const float* ln1_b = (const float*)d_in[9];
  const float* ff_w1 = (const float*)d_in[10];
  const float* ff_b1 = (const float*)d_in[11];
  const float* ff_w2 = (const float*)d_in[12];
  const float* ff_b2 = (const float*)d_in[13];
  const float* ln2_g = (const float*)d_in[14];
  const float* ln2_b = (const float*)d_in[15];
  const float* w_out = (const float*)d_in[16];
  const float* b_out = (const float*)d_in[17];
  float* out = (float*)d_out;
  char* ws = (char*)d_ws;

  // ---- workspace layout (byte offsets; lifetime-audited) ----
  u16* w_in16 = (u16*)(ws + 0);                  // 0-0.25 MiB
  u16* wqkv16 = (u16*)(ws + 262144);             // 0.25-1.75 (wq|wk|wv)
  u16* fw116 = (u16*)(ws + 1835008);             // 1.75-3.75
  u16* fw216 = (u16*)(ws + 3932160);             // 3.75-5.75
  u16* wout16 = (u16*)(ws + 6029312);            // 5.75-6
  u16* u16b = (u16*)(ws + 6291456);              // 6-10   ln_attn -> ff1, ln_ff
  u16* zp = (u16*)(ws + 10485760);               // 10-26  ff2 partials -> ln_ff
  u16* t16 = (u16*)(ws + 14680064);              // 14-18  proj_in -> qkvt, ln_attn
  u16* qb = (u16*)(ws + 18874368);               // 18-22  qkvt -> attn
  u16* kb = (u16*)(ws + 23068672);               // 22-26  qkvt -> attn
  u16* vt = (u16*)(ws + 27262976);               // 26-30  qkvt -> attn
  u16* zb = (u16*)(ws + 27262976);               // 26-30  ln_ff -> proj_out (over vt, dead)
  u16* opart = (u16*)(ws + 31457280);            // 30-46  attn -> ln_attn (4 splits)
  u16* g16 = (u16*)(ws + 31457280);              // 30-46  ff1 -> ff2 (over opart, dead)
  float* ml = (float*)(ws + 48234496);           // 46-46.5 attn -> ln_attn
  u16* hn = (u16*)(ws + 49283072);               // 47-49  gn -> proj_in
  float2* cstats = (float2*)(ws + 51380224);     // 49+

  // weights convert (x4 vectorized, 3072 blocks) + per-channel GN stats (256 blocks)
  f2b_all<<<3328, 256, 0, stream>>>(w_in, wq, wk, wv, ff_w1, ff_w2, w_out, x,
                                    w_in16, wqkv16, fw116, fw216, wout16, cstats);
  gn_apply<<<512, 256, 0, stream>>>(x, cstats, gn_g, gn_b, hn);

  // t = hn @ w_in^T + b_in  -> bf16 (128x64 tiles)
  gemm_bt<<<dim3(32, 8), 256, 0, stream>>>(hn, w_in16, b_in, t16,
                                           4096, 512, 256, FLAG_BIAS | FLAG_C16);
  // fused q|k (+CEXP on q) and V^T, one dispatch, 768 blocks
  gemm_qkvt<<<768, 256, 0, stream>>>(t16, wqkv16, qb, kb, vt);
  // attention: 512 threads, 256q/block, KV-split x4 -> 512 blocks (2/CU)
  attn_kernel<<<dim3(16, 8, 4), 512, 0, stream>>>(qb, kb, vt, opart, ml, 4096, 1024);
  // combine + LN1 (residual from t16) -> bf16
  ln_attn<<<4096, 256, 0, stream>>>(opart, ml, t16, ln1_g, ln1_b, u16b);
  // ff1: gelu(u @ w1^T + b1) -> bf16 (128x64 tiles, 1024 blocks, 3/CU)
  gemm_bt<<<dim3(32, 32), 256, 0, stream>>>(u16b, fw116, ff_b1, g16,
                                            4096, 2048, 512, FLAG_BIAS | FLAG_GELU | FLAG_C16);
  // ff2: split-K x4 -> four bf16 partials (128x64 tiles, 1024 blocks)
  gemm_bt<<<dim3(32, 8, 4), 256, 0, stream>>>(g16, fw216, ff_b2, zp,
                                              4096, 512, 2048, FLAG_BIAS | FLAG_C16 | FLAG_CZ);
  // z = LN(sum zp + u) -> bf16
  ln_ff<<<4096, 256, 0, stream>>>(zp, u16b, ln2_g, ln2_b, zb);
  // out = W_out @ z^T (+b_out per-row, +x), 64x64 tiles, 256 blocks
  gemm_s64<<<dim3(4, 64), 256, 0, stream>>>(wout16, zb, b_out, x, out, 4096, 512);
}

// Round 10
// 212.308 us; speedup vs baseline: 1.0888x; 1.0888x over previous
//
#include <hip/hip_runtime.h>
#include <hip/hip_bf16.h>

typedef unsigned short u16;
typedef __attribute__((ext_vector_type(8))) short short8;
typedef __attribute__((ext_vector_type(4))) float floatx4;
typedef __attribute__((ext_vector_type(16))) float floatx16;
typedef __attribute__((ext_vector_type(4))) unsigned uintx4;

#define LOG2E 1.44269504088896f
#define CEXP (0.125f * LOG2E)   // folded into Q at the QK epilogue

static __device__ __forceinline__ u16 f2b(float f) {
  union { float f; unsigned u; } v; v.f = f;
  unsigned r = v.u + 0x7fffu + ((v.u >> 16) & 1u);
  return (u16)(r >> 16);
}
static __device__ __forceinline__ float b2f(u16 b) {
  union { float f; unsigned u; } v; v.u = ((unsigned)b) << 16;
  return v.f;
}
static __device__ __forceinline__ unsigned pack2bf(float lo, float hi) {
  __hip_bfloat162 a = __float22bfloat162_rn(float2{lo, hi});
  return *(unsigned*)&a;
}
static __device__ __forceinline__ void async16(const u16* g, u16* l) {
  __builtin_amdgcn_global_load_lds(
      (const __attribute__((address_space(1))) unsigned int*)g,
      (__attribute__((address_space(3))) unsigned int*)l, 16, 0, 0);
}
static __device__ __forceinline__ float fexp2(float x) {
  return __builtin_amdgcn_exp2f(x);
}
// row permutation: row-owner block has XCD == (row>>7)%8, so 128-row panels are
// written through the L2 of the XCD that later consumes them.
static __device__ __forceinline__ int rowmap4096(int b) {
  return (b & 7) * 128 + ((b >> 3) & 3) * 1024 + (b >> 5);
}

// ---------------- weights fp32 -> bf16 (x4 vectorized) + per-channel GN stats ----------------
__global__ __launch_bounds__(256) void f2b_all(
    const float* __restrict__ s0, const float* __restrict__ s1, const float* __restrict__ s2,
    const float* __restrict__ s3, const float* __restrict__ s4, const float* __restrict__ s5,
    const float* __restrict__ s6, const float* __restrict__ x,
    u16* __restrict__ d_win, u16* __restrict__ d_qkv, u16* __restrict__ d_f1,
    u16* __restrict__ d_f2, u16* __restrict__ d_wout, float2* __restrict__ cstats) {
  if (blockIdx.x >= 3072) {   // per-channel stats: one block per channel
    int c = blockIdx.x - 3072;
    const float4* p4 = (const float4*)(x + (size_t)c * 4096);
    float s = 0.f, ss = 0.f;
#pragma unroll
    for (int j = 0; j < 4; j++) {
      float4 v = p4[j * 256 + threadIdx.x];
      s += v.x + v.y + v.z + v.w;
      ss += v.x * v.x + v.y * v.y + v.z * v.z + v.w * v.w;
    }
    for (int m = 1; m < 64; m <<= 1) { s += __shfl_xor(s, m); ss += __shfl_xor(ss, m); }
    __shared__ float sb[8];
    int w = threadIdx.x >> 6;
    if ((threadIdx.x & 63) == 0) { sb[w * 2] = s; sb[w * 2 + 1] = ss; }
    __syncthreads();
    if (threadIdx.x == 0)
      cstats[c] = float2{sb[0] + sb[2] + sb[4] + sb[6], sb[1] + sb[3] + sb[5] + sb[7]};
    return;
  }
  int i = blockIdx.x * 256 + threadIdx.x;   // x4 elements per thread
  const float* src;
  u16* dst;
  if (i < 32768) { src = s0; dst = d_win; }
  else if ((i -= 32768) < 65536) { src = s1; dst = d_qkv; }
  else if ((i -= 65536) < 65536) { src = s2; dst = d_qkv + 262144; }
  else if ((i -= 65536) < 65536) { src = s3; dst = d_qkv + 524288; }
  else if ((i -= 65536) < 262144) { src = s4; dst = d_f1; }
  else if ((i -= 262144) < 262144) { src = s5; dst = d_f2; }
  else { i -= 262144; src = s6; dst = d_wout; }   // i in [0, 32768)
  float4 v = *(const float4*)&src[i * 4];
  ushort4 o;
  o.x = f2b(v.x); o.y = f2b(v.y); o.z = f2b(v.z); o.w = f2b(v.w);
  *(ushort4*)&dst[i * 4] = o;
}

// ---------------- GroupNorm apply + LDS transpose to (N,C) bf16, 512 blocks ----------------
__global__ __launch_bounds__(256) void gn_apply(const float* __restrict__ x, const float2* __restrict__ cstats,
                                                const float* __restrict__ gg, const float* __restrict__ gb,
                                                u16* __restrict__ hn) {
  __shared__ float tile[256 * 9];
  __shared__ float gmu[32], grs[32];
  int t = threadIdx.x;
  if (t < 32) {
    float s = 0.f, ss = 0.f;
#pragma unroll
    for (int j = 0; j < 8; j++) { float2 p = cstats[t * 8 + j]; s += p.x; ss += p.y; }
    float mu = s / 32768.f;
    gmu[t] = mu;
    grs[t] = rsqrtf(ss / 32768.f - mu * mu + 1e-5f);
  }
  __syncthreads();
  int bb = blockIdx.x;
  int g = (bb & 7) * 16 + ((bb >> 3) & 3) * 128 + (bb >> 5);   // (g>>4)%8 == bb%8
  int n0 = g * 8;
#pragma unroll
  for (int j = 0; j < 2; j++) {
    int c = j * 128 + (t >> 1);
    int nl = (t & 1) * 4;
    float4 v = *(const float4*)&x[(size_t)c * 4096 + n0 + nl];
    float ga = gg[c] * grs[c >> 3];
    float bb2 = gb[c] - gmu[c >> 3] * ga;
    tile[c * 9 + nl + 0] = v.x * ga + bb2;
    tile[c * 9 + nl + 1] = v.y * ga + bb2;
    tile[c * 9 + nl + 2] = v.z * ga + bb2;
    tile[c * 9 + nl + 3] = v.w * ga + bb2;
  }
  __syncthreads();
#pragma unroll
  for (int j = 0; j < 8; j++)
    hn[(size_t)(n0 + j) * 256 + t] = f2b(tile[t * 9 + j]);
}

#define FLAG_BIAS 1
#define FLAG_GELU 2
#define FLAG_C16 8
#define FLAG_CZ 64      // C16[z*M*N + m*N + n] = bf16(v), bias on z==0 only

// ---------------- GEMM 128x64 tile (proj_in), double-buffered counted-vmcnt pipeline --------
__global__ __launch_bounds__(256) void gemm_bt(
    const u16* __restrict__ A, const u16* __restrict__ B, const float* __restrict__ bias,
    u16* __restrict__ C16, int M, int N, int K, int flags) {
  __shared__ u16 As[2][128 * 64];
  __shared__ u16 Bs[2][64 * 64];
  const int t = threadIdx.x;
  const int lane = t & 63;
  const int w = t >> 6;
  const int ln = lane & 15;
  const int quad = lane >> 4;
  const int m0 = blockIdx.x * 128;
  const int n0 = blockIdx.y * 64;
  const int wm = (w >> 1) * 64;
  const int wn = (w & 1) * 32;

  floatx4 acc[4][2];
#pragma unroll
  for (int i = 0; i < 4; i++)
#pragma unroll
    for (int j = 0; j < 2; j++) acc[i][j] = floatx4{0.f, 0.f, 0.f, 0.f};

  auto stage = [&](int b, int k0) {
#pragma unroll
    for (int i = 0; i < 4; ++i) {
      int s = i * 256 + t;
      int row = s >> 3;
      int kb = (s & 7) ^ (row & 7);
      async16(A + (size_t)(m0 + row) * K + k0 + kb * 8, &As[b][(i * 256 + (t & ~63)) * 8]);
    }
#pragma unroll
    for (int i = 0; i < 2; ++i) {
      int s = i * 256 + t;
      int row = s >> 3;
      int kb = (s & 7) ^ (row & 7);
      async16(B + (size_t)(n0 + row) * K + k0 + kb * 8, &Bs[b][(i * 256 + (t & ~63)) * 8]);
    }
  };

  const int nIt = K >> 6;
  stage(0, 0);
  int cur = 0;
  for (int it = 0; it < nIt; ++it) {
    __builtin_amdgcn_s_barrier();
    __builtin_amdgcn_sched_barrier(0);
    if (it + 1 < nIt) {
      stage(cur ^ 1, (it + 1) * 64);
      __builtin_amdgcn_sched_barrier(0);
      asm volatile("s_waitcnt vmcnt(6)" ::: "memory");   // drain tile it; 6 new stay in flight
    } else {
      asm volatile("s_waitcnt vmcnt(0)" ::: "memory");
    }
    __builtin_amdgcn_s_barrier();
    __builtin_amdgcn_sched_barrier(0);
    const u16* Ac = As[cur];
    const u16* Bc = Bs[cur];
#pragma unroll
    for (int ksi = 0; ksi < 2; ksi++) {
      short8 af[4], bfr[2];
      int kb = ksi * 4 + quad;
#pragma unroll
      for (int i = 0; i < 4; i++) {
        int m = wm + i * 16 + ln;
        af[i] = *(const short8*)&Ac[(m * 8 + (kb ^ (m & 7))) * 8];
      }
#pragma unroll
      for (int j = 0; j < 2; j++) {
        int n = wn + j * 16 + ln;
        bfr[j] = *(const short8*)&Bc[(n * 8 + (kb ^ (n & 7))) * 8];
      }
#pragma unroll
      for (int i = 0; i < 4; i++)
#pragma unroll
        for (int j = 0; j < 2; j++)
          acc[i][j] = __builtin_amdgcn_mfma_f32_16x16x32_bf16(af[i], bfr[j], acc[i][j], 0, 0, 0);
    }
    cur ^= 1;
  }

#pragma unroll
  for (int i = 0; i < 4; i++) {
#pragma unroll
    for (int j = 0; j < 2; j++) {
      int n = n0 + wn + j * 16 + ln;
      float bv = (flags & FLAG_BIAS) ? bias[n] : 0.f;
#pragma unroll
      for (int r = 0; r < 4; r++) {
        int m = m0 + wm + i * 16 + quad * 4 + r;
        float v = acc[i][j][r] + bv;
        if (flags & FLAG_C16) C16[(size_t)m * N + n] = f2b(v);
      }
    }
  }
}

// ---------------- GEMM 64x64 tile (proj_out: row-bias + resid fp32), pipelined ----------------
__global__ __launch_bounds__(256) void gemm_s64(
    const u16* __restrict__ A, const u16* __restrict__ B, const float* __restrict__ brow,
    const float* __restrict__ resid, float* __restrict__ C32, int N, int K) {
  __shared__ u16 As[2][64 * 64];
  __shared__ u16 Bs[2][64 * 64];
  const int t = threadIdx.x;
  const int lane = t & 63;
  const int w = t >> 6;
  const int ln = lane & 15;
  const int quad = lane >> 4;
  const int f = blockIdx.x + 4 * blockIdx.y;   // hw flat id; XCD = f%8
  const int x = f & 7;
  const int idx = f >> 3;                      // [0,32)
  const int j5 = idx & 7;
  const int nbx = idx >> 3;                    // [0,4)
  const int nby = 2 * x + (j5 & 1) + 16 * (j5 >> 1);  // (nby>>1)%8 == x
  const int m0 = nbx * 64;
  const int n0 = nby * 64;
  const int wm = (w >> 1) * 32;
  const int wn = (w & 1) * 32;

  floatx4 acc[2][2];
#pragma unroll
  for (int i = 0; i < 2; i++)
#pragma unroll
    for (int j = 0; j < 2; j++) acc[i][j] = floatx4{0.f, 0.f, 0.f, 0.f};

  auto stage = [&](int b, int k0) {
#pragma unroll
    for (int i = 0; i < 2; ++i) {
      int s = i * 256 + t;
      int row = s >> 3;
      int kb = (s & 7) ^ (row & 7);
      async16(A + (size_t)(m0 + row) * K + k0 + kb * 8, &As[b][(i * 256 + (t & ~63)) * 8]);
    }
#pragma unroll
    for (int i = 0; i < 2; ++i) {
      int s = i * 256 + t;
      int row = s >> 3;
      int kb = (s & 7) ^ (row & 7);
      async16(B + (size_t)(n0 + row) * K + k0 + kb * 8, &Bs[b][(i * 256 + (t & ~63)) * 8]);
    }
  };

  const int nIt = K >> 6;
  stage(0, 0);
  int cur = 0;
  for (int it = 0; it < nIt; ++it) {
    __builtin_amdgcn_s_barrier();
    __builtin_amdgcn_sched_barrier(0);
    if (it + 1 < nIt) {
      stage(cur ^ 1, (it + 1) * 64);
      __builtin_amdgcn_sched_barrier(0);
      asm volatile("s_waitcnt vmcnt(4)" ::: "memory");
    } else {
      asm volatile("s_waitcnt vmcnt(0)" ::: "memory");
    }
    __builtin_amdgcn_s_barrier();
    __builtin_amdgcn_sched_barrier(0);
    const u16* Ac = As[cur];
    const u16* Bc = Bs[cur];
#pragma unroll
    for (int ksi = 0; ksi < 2; ksi++) {
      short8 af[2], bfr[2];
      int kb = ksi * 4 + quad;
#pragma unroll
      for (int i = 0; i < 2; i++) {
        int m = wm + i * 16 + ln;
        af[i] = *(const short8*)&Ac[(m * 8 + (kb ^ (m & 7))) * 8];
        int n = wn + i * 16 + ln;
        bfr[i] = *(const short8*)&Bc[(n * 8 + (kb ^ (n & 7))) * 8];
      }
#pragma unroll
      for (int i = 0; i < 2; i++)
#pragma unroll
        for (int j = 0; j < 2; j++)
          acc[i][j] = __builtin_amdgcn_mfma_f32_16x16x32_bf16(af[i], bfr[j], acc[i][j], 0, 0, 0);
    }
    cur ^= 1;
  }

#pragma unroll
  for (int i = 0; i < 2; i++) {
#pragma unroll
    for (int j = 0; j < 2; j++) {
      int n = n0 + wn + j * 16 + ln;
#pragma unroll
      for (int r = 0; r < 4; r++) {
        int m = m0 + wm + i * 16 + quad * 4 + r;
        C32[(size_t)m * N + n] = acc[i][j][r] + brow[m] + resid[(size_t)m * N + n];
      }
    }
  }
}

// ---------------- GEMM 128x128 tile (ff1, ff2 split-K bf16 partials), 512 thr, pipelined ----
__global__ __launch_bounds__(512) void gemm_big(
    const u16* __restrict__ A, const u16* __restrict__ B, const float* __restrict__ bias,
    u16* __restrict__ C16, int M, int N, int K, int flags) {
  __shared__ u16 As[2][128 * 64];
  __shared__ u16 Bs[2][128 * 64];
  const int t = threadIdx.x;
  const int lane = t & 63;
  const int w = t >> 6;            // 0..7
  const int ln = lane & 15;
  const int quad = lane >> 4;

  const int m0 = blockIdx.x * 128;
  const int n0 = blockIdx.y * 128;
  const int wm = (w >> 2) * 64;    // 2 m-halves
  const int wn = (w & 3) * 32;     // 4 n-quarters
  const int kper = K / gridDim.z;
  const int kbeg = blockIdx.z * kper;

  floatx4 acc[4][2];
#pragma unroll
  for (int i = 0; i < 4; i++)
#pragma unroll
    for (int j = 0; j < 2; j++) acc[i][j] = floatx4{0.f, 0.f, 0.f, 0.f};

  auto stage = [&](int b, int k0) {
#pragma unroll
    for (int i = 0; i < 2; ++i) {
      int s = i * 512 + t;
      int row = s >> 3;
      int kb = (s & 7) ^ (row & 7);
      async16(A + (size_t)(m0 + row) * K + k0 + kb * 8, &As[b][(i * 512 + (t & ~63)) * 8]);
      async16(B + (size_t)(n0 + row) * K + k0 + kb * 8, &Bs[b][(i * 512 + (t & ~63)) * 8]);
    }
  };

  const int nIt = kper >> 6;
  stage(0, kbeg);
  int cur = 0;
  for (int it = 0; it < nIt; ++it) {
    __builtin_amdgcn_s_barrier();
    __builtin_amdgcn_sched_barrier(0);
    if (it + 1 < nIt) {
      stage(cur ^ 1, kbeg + (it + 1) * 64);
      __builtin_amdgcn_sched_barrier(0);
      asm volatile("s_waitcnt vmcnt(4)" ::: "memory");   // drain tile it; 4 new stay in flight
    } else {
      asm volatile("s_waitcnt vmcnt(0)" ::: "memory");
    }
    __builtin_amdgcn_s_barrier();
    __builtin_amdgcn_sched_barrier(0);
    const u16* Ac = As[cur];
    const u16* Bc = Bs[cur];
#pragma unroll
    for (int ksi = 0; ksi < 2; ksi++) {
      short8 af[4], bfr[2];
      int kb = ksi * 4 + quad;
#pragma unroll
      for (int i = 0; i < 4; i++) {
        int m = wm + i * 16 + ln;
        af[i] = *(const short8*)&Ac[(m * 8 + (kb ^ (m & 7))) * 8];
      }
#pragma unroll
      for (int j = 0; j < 2; j++) {
        int n = wn + j * 16 + ln;
        bfr[j] = *(const short8*)&Bc[(n * 8 + (kb ^ (n & 7))) * 8];
      }
#pragma unroll
      for (int i = 0; i < 4; i++)
#pragma unroll
        for (int j = 0; j < 2; j++)
          acc[i][j] = __builtin_amdgcn_mfma_f32_16x16x32_bf16(af[i], bfr[j], acc[i][j], 0, 0, 0);
    }
    cur ^= 1;
  }

  u16* Cdst = (flags & FLAG_CZ) ? C16 + (size_t)blockIdx.z * M * N : C16;
#pragma unroll
  for (int i = 0; i < 4; i++) {
#pragma unroll
    for (int j = 0; j < 2; j++) {
      int n = n0 + wn + j * 16 + ln;
      float bv = ((flags & FLAG_BIAS) && blockIdx.z == 0) ? bias[n] : 0.f;
#pragma unroll
      for (int r = 0; r < 4; r++) {
        int m = m0 + wm + i * 16 + quad * 4 + r;
        float v = acc[i][j][r] + bv;
        if (flags & FLAG_GELU) v = 0.5f * v * (1.f + erff(v * 0.70710678118f));
        Cdst[(size_t)m * N + n] = f2b(v);
      }
    }
  }
}

// ---------------- merged q|k + V^T GEMM, 64x128 tiles, one dispatch, pipelined ----------------
__global__ __launch_bounds__(256) void gemm_qkvt(
    const u16* __restrict__ T, const u16* __restrict__ Wqkv,
    u16* __restrict__ Cq, u16* __restrict__ Ck, u16* __restrict__ CvT) {
  __shared__ u16 As[2][64 * 64];
  __shared__ u16 Bs[2][128 * 64];
  const int t = threadIdx.x;
  const int lane = t & 63;
  const int w = t >> 6;
  const int ln = lane & 15;
  const int quad = lane >> 4;
  const int f = blockIdx.x;        // hw flat; XCD = f%8
  const bool isv = f >= 512;
  const u16* A;
  const u16* B;
  int m0, n0;
  if (!isv) {
    int x = f & 7, idx = f >> 3;
    int j5 = idx & 7, nt = idx >> 3;
    int mt = 2 * x + (j5 & 1) + 16 * (j5 >> 1);
    m0 = mt * 64;
    n0 = nt * 128;
    A = T;
    B = Wqkv;
  } else {
    int b2 = f - 512;
    int x = b2 & 7, idx = b2 >> 3;
    int nt2 = x + 8 * (idx & 3);
    int mt2 = idx >> 2;
    m0 = mt2 * 64;
    n0 = nt2 * 128;
    A = Wqkv + 2 * 512 * 512;   // wv
    B = T;
  }
  const int wm = (w >> 1) * 32;
  const int wn = (w & 1) * 64;

  floatx4 acc[2][4];
#pragma unroll
  for (int i = 0; i < 2; i++)
#pragma unroll
    for (int j = 0; j < 4; j++) acc[i][j] = floatx4{0.f, 0.f, 0.f, 0.f};

  auto stage = [&](int b, int k0) {
#pragma unroll
    for (int i = 0; i < 2; ++i) {
      int s = i * 256 + t;
      int row = s >> 3;
      int kb = (s & 7) ^ (row & 7);
      async16(A + (size_t)(m0 + row) * 512 + k0 + kb * 8, &As[b][(i * 256 + (t & ~63)) * 8]);
    }
#pragma unroll
    for (int i = 0; i < 4; ++i) {
      int s = i * 256 + t;
      int row = s >> 3;
      int kb = (s & 7) ^ (row & 7);
      async16(B + (size_t)(n0 + row) * 512 + k0 + kb * 8, &Bs[b][(i * 256 + (t & ~63)) * 8]);
    }
  };

  stage(0, 0);
  int cur = 0;
  for (int it = 0; it < 8; ++it) {
    __builtin_amdgcn_s_barrier();
    __builtin_amdgcn_sched_barrier(0);
    if (it + 1 < 8) {
      stage(cur ^ 1, (it + 1) * 64);
      __builtin_amdgcn_sched_barrier(0);
      asm volatile("s_waitcnt vmcnt(6)" ::: "memory");
    } else {
      asm volatile("s_waitcnt vmcnt(0)" ::: "memory");
    }
    __builtin_amdgcn_s_barrier();
    __builtin_amdgcn_sched_barrier(0);
    const u16* Ac = As[cur];
    const u16* Bc = Bs[cur];
#pragma unroll
    for (int ksi = 0; ksi < 2; ksi++) {
      short8 af[2], bfr[4];
      int kb = ksi * 4 + quad;
#pragma unroll
      for (int i = 0; i < 2; i++) {
        int m = wm + i * 16 + ln;
        af[i] = *(const short8*)&Ac[(m * 8 + (kb ^ (m & 7))) * 8];
      }
#pragma unroll
      for (int j = 0; j < 4; j++) {
        int n = wn + j * 16 + ln;
        bfr[j] = *(const short8*)&Bc[(n * 8 + (kb ^ (n & 7))) * 8];
      }
#pragma unroll
      for (int i = 0; i < 2; i++)
#pragma unroll
        for (int j = 0; j < 4; j++)
          acc[i][j] = __builtin_amdgcn_mfma_f32_16x16x32_bf16(af[i], bfr[j], acc[i][j], 0, 0, 0);
    }
    cur ^= 1;
  }

#pragma unroll
  for (int i = 0; i < 2; i++) {
#pragma unroll
    for (int j = 0; j < 4; j++) {
      int n = n0 + wn + j * 16 + ln;
#pragma unroll
      for (int r = 0; r < 4; r++) {
        int m = m0 + wm + i * 16 + quad * 4 + r;
        float v = acc[i][j][r];
        if (isv) CvT[(size_t)m * 4096 + n] = f2b(v);
        else if (n < 512) Cq[(size_t)m * 512 + n] = f2b(v * CEXP);   // Q pre-scaled
        else Ck[(size_t)m * 512 + (n - 512)] = f2b(v);
      }
    }
  }
}

// ---------------- flash attention: KVBLK=128 per barrier-iteration (nIt=8) -------------------
// 512 threads, 8 waves x 32 q. Per iteration: stage 128-key K tile + 128-kv V tile (dbuf,
// counted vmcnt(4)); compute processes the tile as two sequential 64-key halves with the
// verified R7 per-half body (accS reused -> R7 register footprint). Fixed per-iteration
// barrier/latency overhead is paid 8x instead of 16x.
__global__ __launch_bounds__(512, 4) void attn_kernel(
    const u16* __restrict__ Q, const u16* __restrict__ Km, const u16* __restrict__ VT,
    u16* __restrict__ Opart, float* __restrict__ ML, int Nseq, int kvLen) {
  __shared__ u16 Ks[2][128 * 64];   // [key][hd] swizzled, 16 KiB
  __shared__ u16 Vs[2][64 * 128];   // [d][kv] swizzled, 16 KiB
  const int t = threadIdx.x;
  const int lane = t & 63;
  const int w = t >> 6;            // 0..7
  const int q32 = lane & 31;       // q column within wave tile
  const int H = lane >> 5;         // lane half
  const int h = blockIdx.y;
  const int q0 = blockIdx.x * 256;
  const int split = blockIdx.z;
  const int kvbase = split * kvLen;
  u16* Opw = Opart + (size_t)split * Nseq * 512;

  // Q B-operand fragments qf[kc]: k = kc*16 + H*8 + v (v=0..7 contiguous bf16)
  short8 qf[4];
#pragma unroll
  for (int kc = 0; kc < 4; kc++)
    qf[kc] = *(const short8*)&Q[(size_t)(q0 + w * 32 + q32) * 512 + h * 64 + kc * 16 + H * 8];

  floatx16 accO[2];
#pragma unroll
  for (int dt = 0; dt < 2; dt++)
#pragma unroll
    for (int r = 0; r < 16; r++) accO[dt][r] = 0.f;
  float lsum = 0.f;

  const int nIt = kvLen >> 7;      // 128 keys per iteration

  // staging: 4 x 16B chunks per thread per tile (2 K passes + 2 V passes)
  auto stageTile = [&](int b, int kv0) {
#pragma unroll
    for (int i = 0; i < 2; ++i) {
      int s = i * 512 + t;
      int krow = s >> 3;                      // 0..127
      int kkb = (s & 7) ^ (krow & 7);         // swizzled hd-chunk
      async16(Km + (size_t)(kvbase + kv0 + krow) * 512 + h * 64 + kkb * 8,
              &Ks[b][(i * 512 + (t & ~63)) * 8]);
    }
#pragma unroll
    for (int i = 0; i < 2; ++i) {
      int s = i * 512 + t;
      int d = s >> 4;                         // 0..63
      int c = s & 15;                         // kv-chunk slot 0..15
      int cs = c ^ (d & 7);                   // swizzled kv-chunk
      async16(VT + (size_t)(h * 64 + d) * Nseq + kvbase + kv0 + cs * 8,
              &Vs[b][(i * 512 + (t & ~63)) * 8]);
    }
  };

  stageTile(0, 0);
  int cur = 0;
  for (int it = 0; it < nIt; ++it) {
    // barrier A: all waves finished reading buf[cur^1] before refill
    __builtin_amdgcn_s_barrier();
    __builtin_amdgcn_sched_barrier(0);
    if (it + 1 < nIt) {
      stageTile(cur ^ 1, (it + 1) * 128);
      __builtin_amdgcn_sched_barrier(0);
      asm volatile("s_waitcnt vmcnt(4)" ::: "memory");   // tile it done; 4 new in flight
    } else {
      __builtin_amdgcn_sched_barrier(0);
      asm volatile("s_waitcnt vmcnt(0)" ::: "memory");
    }
    // barrier B: tile `it` visible to all waves
    __builtin_amdgcn_s_barrier();
    __builtin_amdgcn_sched_barrier(0);

    const u16* Kc = Ks[cur];
    const u16* Vc = Vs[cur];

#pragma unroll
    for (int half = 0; half < 2; ++half) {
      // S^T[key][q] for keys half*64 .. half*64+63 (two 32-key tiles)
      floatx16 accS[2];
#pragma unroll
      for (int kt = 0; kt < 2; kt++)
#pragma unroll
        for (int r = 0; r < 16; r++) accS[kt][r] = 0.f;
      __builtin_amdgcn_s_setprio(1);
#pragma unroll
      for (int kt = 0; kt < 2; kt++) {
        int key = half * 64 + kt * 32 + q32;   // A-row for this lane
#pragma unroll
        for (int kc = 0; kc < 4; kc++) {
          int hb = kc * 2 + H;     // 8-elem hd-block
          short8 kf = *(const short8*)&Kc[(key * 8 + (hb ^ (key & 7))) * 8];
          accS[kt] = __builtin_amdgcn_mfma_f32_32x32x16_bf16(kf, qf[kc], accS[kt], 0, 0, 0);
        }
      }
      __builtin_amdgcn_s_setprio(0);

      // p = exp2(s) in place (static indices); lsum
#pragma unroll
      for (int kt = 0; kt < 2; kt++)
#pragma unroll
        for (int r = 0; r < 16; r++) {
          float pv = fexp2(accS[kt][r]);
          accS[kt][r] = pv;
          lsum += pv;
        }

      // build P B-fragments in-register and do PV immediately per kch
      __builtin_amdgcn_s_setprio(1);
#pragma unroll
      for (int kch = 0; kch < 4; kch++) {
        const int KT = kch >> 1;
        const int S8 = (kch & 1) * 8;
        // lane-half select with STATIC vector extracts (runtime H only in cndmask)
        float e0 = H ? accS[KT][S8 + 4] : accS[KT][S8 + 0];
        float e1 = H ? accS[KT][S8 + 5] : accS[KT][S8 + 1];
        float e2 = H ? accS[KT][S8 + 6] : accS[KT][S8 + 2];
        float e3 = H ? accS[KT][S8 + 7] : accS[KT][S8 + 3];
        unsigned pk0 = pack2bf(e0, e1);
        unsigned pk1 = pack2bf(e2, e3);
        unsigned rx0 = __shfl_xor(pk0, 32);
        unsigned rx1 = __shfl_xor(pk1, 32);
        uintx4 pwv;
        pwv.x = H ? rx0 : pk0;
        pwv.y = H ? rx1 : pk1;
        pwv.z = H ? pk0 : rx0;
        pwv.w = H ? pk1 : rx1;
        short8 pf = __builtin_bit_cast(short8, pwv);
        int kb2 = half * 8 + kch * 2 + H;   // 8-key block within the 128-kv V tile
#pragma unroll
        for (int dt = 0; dt < 2; dt++) {
          int d = dt * 32 + q32;     // A-row for this lane
          short8 vf = *(const short8*)&Vc[(d * 16 + (kb2 ^ (d & 7))) * 8];
          accO[dt] = __builtin_amdgcn_mfma_f32_32x32x16_bf16(vf, pf, accO[dt], 0, 0, 0);
        }
      }
      __builtin_amdgcn_s_setprio(0);
    }
    cur ^= 1;
  }

  lsum += __shfl_xor(lsum, 32);
  const int q = q0 + w * 32 + q32;
#pragma unroll
  for (int dt = 0; dt < 2; dt++) {
#pragma unroll
    for (int g = 0; g < 4; g++) {
      // regs 4g..4g+3 -> d = dt*32 + 8g + 4H + (0..3)
      uint2 pk;
      pk.x = pack2bf(accO[dt][4 * g + 0], accO[dt][4 * g + 1]);
      pk.y = pack2bf(accO[dt][4 * g + 2], accO[dt][4 * g + 3]);
      *(uint2*)&Opw[(size_t)q * 512 + h * 64 + dt * 32 + 8 * g + 4 * H] = pk;
    }
  }
  if (H == 0)
    ML[((size_t)split * 8 + h) * Nseq + q] = lsum;
}

// ---------------- combine 4 splits + bf16 residual + LayerNorm (ln1) -> bf16 ----------------
__global__ __launch_bounds__(256) void ln_attn(
    const u16* __restrict__ Opart, const float* __restrict__ ML,
    const u16* __restrict__ t16, const float* __restrict__ g, const float* __restrict__ be,
    u16* __restrict__ o16) {
  int row = rowmap4096(blockIdx.x);
  int t = threadIdx.x;
  size_t base = (size_t)row * 512;
  int c0 = 2 * t;
  int h = c0 >> 6;
  float lt = 0.f;
#pragma unroll
  for (int s = 0; s < 4; s++) lt += ML[((size_t)s * 8 + h) * 4096 + row];
  float a0 = 0.f, a1 = 0.f;
#pragma unroll
  for (int s = 0; s < 4; s++) {
    unsigned oo = *(const unsigned*)&Opart[(size_t)s * 4096 * 512 + base + c0];
    a0 += b2f((u16)(oo & 0xffff));
    a1 += b2f((u16)(oo >> 16));
  }
  unsigned tt = *(const unsigned*)&t16[base + c0];
  float inv = 1.0f / lt;
  float v0 = a0 * inv + b2f((u16)(tt & 0xffff));
  float v1 = a1 * inv + b2f((u16)(tt >> 16));
  float s = v0 + v1, ss = v0 * v0 + v1 * v1;
  for (int m = 1; m < 64; m <<= 1) { s += __shfl_xor(s, m); ss += __shfl_xor(ss, m); }
  __shared__ float sb[8];
  int w = t >> 6;
  if ((t & 63) == 0) { sb[w * 2] = s; sb[w * 2 + 1] = ss; }
  __syncthreads();
  s = sb[0] + sb[2] + sb[4] + sb[6];
  ss = sb[1] + sb[3] + sb[5] + sb[7];
  float mu = s / 512.f;
  float var = ss / 512.f - mu * mu;
  float rs = rsqrtf(var + 1e-5f);
  float2 gv = *(const float2*)&g[c0];
  float2 bv = *(const float2*)&be[c0];
  u16 r0 = f2b((v0 - mu) * rs * gv.x + bv.x);
  u16 r1 = f2b((v1 - mu) * rs * gv.y + bv.y);
  *(unsigned*)&o16[base + c0] = ((unsigned)r1 << 16) | r0;
}

// ---------------- LN2: (4 bf16 split-K partials + bf16 u) -> LayerNorm -> bf16 ----------------
__global__ __launch_bounds__(256) void ln_ff(
    const u16* __restrict__ zp, const u16* __restrict__ u,
    const float* __restrict__ g, const float* __restrict__ be, u16* __restrict__ o16) {
  int row = rowmap4096(blockIdx.x);
  int t = threadIdx.x;
  size_t base = (size_t)row * 512;
  int c0 = 2 * t;
  unsigned uu = *(const unsigned*)&u[base + c0];
  float v0 = b2f((u16)(uu & 0xffff));
  float v1 = b2f((u16)(uu >> 16));
#pragma unroll
  for (int z = 0; z < 4; z++) {
    unsigned zz = *(const unsigned*)&zp[(size_t)z * 4096 * 512 + base + c0];
    v0 += b2f((u16)(zz & 0xffff));
    v1 += b2f((u16)(zz >> 16));
  }
  float s = v0 + v1, ss = v0 * v0 + v1 * v1;
  for (int m = 1; m < 64; m <<= 1) { s += __shfl_xor(s, m); ss += __shfl_xor(ss, m); }
  __shared__ float sb[8];
  int w = t >> 6;
  if ((t & 63) == 0) { sb[w * 2] = s; sb[w * 2 + 1] = ss; }
  __syncthreads();
  s = sb[0] + sb[2] + sb[4] + sb[6];
  ss = sb[1] + sb[3] + sb[5] + sb[7];
  float mu = s / 512.f;
  float var = ss / 512.f - mu * mu;
  float rs = rsqrtf(var + 1e-5f);
  float2 gv = *(const float2*)&g[c0];
  float2 bv = *(const float2*)&be[c0];
  u16 r0 = f2b((v0 - mu) * rs * gv.x + bv.x);
  u16 r1 = f2b((v1 - mu) * rs * gv.y + bv.y);
  *(unsigned*)&o16[base + c0] = ((unsigned)r1 << 16) | r0;
}

extern "C" void kernel_launch(void* const* d_in, const int* in_sizes, int n_in,
                              void* d_out, int out_size, void* d_ws, size_t ws_size,
                              hipStream_t stream) {
  const float* x = (const float*)d_in[0];
  const float* gn_g = (const float*)d_in[1];
  const float* gn_b = (const float*)d_in[2];
  const float* w_in = (const float*)d_in[3];
  const float* b_in = (const float*)d_in[4];
  const float* wq = (const float*)d_in[5];
  const float* wk = (const float*)d_in[6];
  const float* wv = (const float*)d_in[7];
  const float* ln1_g = (const float*)d_in[8];
  const float* ln1_b = (const float*)d_in[9];
  const float* ff_w1 = (const float*)d_in[10];
  const float* ff_b1 = (const float*)d_in[11];
  const float* ff_w2 = (const float*)d_in[12];
  const float* ff_b2 = (const float*)d_in[13];
  const float* ln2_g = (const float*)d_in[14];
  const float* ln2_b = (const float*)d_in[15];
  const float* w_out = (const float*)d_in[16];
  const float* b_out = (const float*)d_in[17];
  float* out = (float*)d_out;
  char* ws = (char*)d_ws;

  // ---- workspace layout (byte offsets; lifetime-audited) ----
  u16* w_in16 = (u16*)(ws + 0);                  // 0-0.25 MiB
  u16* wqkv16 = (u16*)(ws + 262144);             // 0.25-1.75 (wq|wk|wv)
  u16* fw116 = (u16*)(ws + 1835008);             // 1.75-3.75
  u16* fw216 = (u16*)(ws + 3932160);             // 3.75-5.75
  u16* wout16 = (u16*)(ws + 6029312);            // 5.75-6
  u16* u16b = (u16*)(ws + 6291456);              // 6-10   ln_attn -> ff1, ln_ff
  u16* zp = (u16*)(ws + 10485760);               // 10-26  ff2 partials -> ln_ff
  u16* t16 = (u16*)(ws + 14680064);              // 14-18  proj_in -> qkvt, ln_attn
  u16* qb = (u16*)(ws + 18874368);               // 18-22  qkvt -> attn
  u16* kb = (u16*)(ws + 23068672);               // 22-26  qkvt -> attn
  u16* vt = (u16*)(ws + 27262976);               // 26-30  qkvt -> attn
  u16* zb = (u16*)(ws + 27262976);               // 26-30  ln_ff -> proj_out (over vt, dead)
  u16* opart = (u16*)(ws + 31457280);            // 30-46  attn -> ln_attn (4 splits)
  u16* g16 = (u16*)(ws + 31457280);              // 30-46  ff1 -> ff2 (over opart, dead)
  float* ml = (float*)(ws + 48234496);           // 46-46.5 attn -> ln_attn
  u16* hn = (u16*)(ws + 49283072);               // 47-49  gn -> proj_in
  float2* cstats = (float2*)(ws + 51380224);     // 49+

  // weights convert (x4 vectorized, 3072 blocks) + per-channel GN stats (256 blocks)
  f2b_all<<<3328, 256, 0, stream>>>(w_in, wq, wk, wv, ff_w1, ff_w2, w_out, x,
                                    w_in16, wqkv16, fw116, fw216, wout16, cstats);
  gn_apply<<<512, 256, 0, stream>>>(x, cstats, gn_g, gn_b, hn);

  // t = hn @ w_in^T + b_in  -> bf16 (128x64 tiles)
  gemm_bt<<<dim3(32, 8), 256, 0, stream>>>(hn, w_in16, b_in, t16,
                                           4096, 512, 256, FLAG_BIAS | FLAG_C16);
  // fused q|k (+CEXP on q) and V^T, one dispatch, 768 blocks
  gemm_qkvt<<<768, 256, 0, stream>>>(t16, wqkv16, qb, kb, vt);
  // attention: 512 threads, 256q/block, KVBLK=128 -> 8 barrier-iterations, KV-split x4
  attn_kernel<<<dim3(16, 8, 4), 512, 0, stream>>>(qb, kb, vt, opart, ml, 4096, 1024);
  // combine + LN1 (residual from t16) -> bf16
  ln_attn<<<4096, 256, 0, stream>>>(opart, ml, t16, ln1_g, ln1_b, u16b);
  // ff1: gelu(u @ w1^T + b1) -> bf16  (128x128 tiles, 512 threads — R7 config)
  gemm_big<<<dim3(32, 16), 512, 0, stream>>>(u16b, fw116, ff_b1, g16,
                                             4096, 2048, 512, FLAG_BIAS | FLAG_GELU | FLAG_C16);
  // ff2: split-K x4 -> four bf16 partials (128x128 tiles, 512 threads)
  gemm_big<<<dim3(32, 4, 4), 512, 0, stream>>>(g16, fw216, ff_b2, zp,
                                               4096, 512, 2048, FLAG_BIAS | FLAG_CZ);
  // z = LN(sum zp + u) -> bf16
  ln_ff<<<4096, 256, 0, stream>>>(zp, u16b, ln2_g, ln2_b, zb);
  // out = W_out @ z^T (+b_out per-row, +x), 64x64 tiles, 256 blocks
  gemm_s64<<<dim3(4, 64), 256, 0, stream>>>(wout16, zb, b_out, x, out, 4096, 512);
}